// Round 7
// baseline (267.798 us; speedup 1.0000x reference)
//
#include <hip/hip_runtime.h>

typedef __bf16 bf16x8 __attribute__((ext_vector_type(8)));
typedef float f32x4 __attribute__((ext_vector_type(4)));
typedef unsigned short u16;

__device__ __forceinline__ u16 f2b(float f) {
  unsigned u = __builtin_bit_cast(unsigned, f);
  u = (u + 0x7FFFu + ((u >> 16) & 1u)) >> 16;
  return (u16)u;
}
__device__ __forceinline__ float b2f(u16 h) {
  return __builtin_bit_cast(float, (unsigned)h << 16);
}

// async global->LDS, 16B per lane. dst = wave-uniform base + lane*16.
__device__ __forceinline__ void glds16(const u16* g, u16* l) {
  __builtin_amdgcn_global_load_lds(
      (const __attribute__((address_space(1))) unsigned*)g,
      (__attribute__((address_space(3))) unsigned*)l, 16, 0, 0);
}

// ---------------------------------------------------------------------------
// Swizzled layouts (16B = 8-u16 units, BK=32 K-tiles), M-block = 96 rows:
// X [24576,256]: q -> b=q/96, m=q%96; c -> kt=c>>5, g=(c>>3)&3, j=c&7;
//   u = m*4 + (g ^ ((m>>1)&3));  elem off = b*24576 + kt*3072 + u*8 + j
// W [256,K]: n,c -> kt=c>>5, g=(c>>3)&3, j=c&7; u = n*4 + (g^((n>>1)&3));
//   off = kt*8192 + u*8 + j
// H (LDS, 96x256): m,k -> g=k>>3; u = m*32 + (g ^ ((m>>1)&7))
// ---------------------------------------------------------------------------

// ---------------------------------------------------------------------------
// Column decode table: col -> (src scalar idx, freq, kind)
// kind: 0 raw, 1 sin, 2 cos, 3 zero.  enc = src | f<<5 | kind<<9
// ---------------------------------------------------------------------------
struct FT {
  u16 v[256];
  static constexpr u16 enc(int s, int f, int k) {
    return (u16)(s | (f << 5) | (k << 9));
  }
  constexpr void p3(int base, int F, int src) {
    v[base + 0] = enc(src + 0, 0, 0);
    v[base + 1] = enc(src + 1, 0, 0);
    v[base + 2] = enc(src + 2, 0, 0);
    for (int f = 0; f < F; ++f)
      for (int r = 0; r < 6; ++r) {
        int comp = (r < 3) ? r : r - 3;
        v[base + 3 + f * 6 + r] = enc(src + comp, f, (r < 3) ? 1 : 2);
      }
  }
  constexpr void p1(int base, int F, int src) {
    v[base] = enc(src, 0, 0);
    for (int f = 0; f < F; ++f) {
      v[base + 1 + 2 * f] = enc(src, f, 1);
      v[base + 2 + 2 * f] = enc(src, f, 2);
    }
  }
  constexpr FT() : v{} {
    p3(0, 10, 0);     // hit_pos_emb   (q)          [0..62]
    p1(63, 4, 3);     // density_emb                [63..71]
    p3(72, 10, 4);    // smoothed_emb  (sp)         [72..134]
    p3(135, 10, 7);   // var_emb       (var)        [135..197]
    p3(198, 4, 10);   // hit_dir_emb   (ray dir)    [198..224]
    p3(225, 4, 13);   // dirs_emb      (dir)        [225..251]
    v[252] = enc(16, 0, 0);  // normals
    v[253] = enc(17, 0, 0);
    v[254] = enc(18, 0, 0);
    v[255] = enc(0, 0, 3);   // pad col
  }
};
__constant__ FT ftab = FT();

// ---------------------------------------------------------------------------
// Kernel 1: weight prep fp32 -> split bf16 planes, BK=32 swizzled layout.
// W0 [256,511] -> [256,512]: col 255 = 0, cols 256..511 = orig 255..510.
// ---------------------------------------------------------------------------
__global__ __launch_bounds__(256) void prep_weights(
    const float* __restrict__ W0, const float* __restrict__ W1,
    const float* __restrict__ W2,
    u16* __restrict__ w0h, u16* __restrict__ w0l,
    u16* __restrict__ w1h, u16* __restrict__ w1l,
    u16* __restrict__ w2h, u16* __restrict__ w2l)
{
  int i = blockIdx.x * 256 + threadIdx.x;   // 0 .. 262143
  float v; u16 *ph, *pl; int n, c;
  if (i < 131072) {
    n = i >> 9; c = i & 511;
    v = (c < 255) ? W0[n * 511 + c] : ((c == 255) ? 0.0f : W0[n * 511 + (c - 1)]);
    ph = w0h; pl = w0l;
  } else if (i < 196608) {
    int j = i - 131072; n = j >> 8; c = j & 255; v = W1[j]; ph = w1h; pl = w1l;
  } else {
    int j = i - 196608; n = j >> 8; c = j & 255; v = W2[j]; ph = w2h; pl = w2l;
  }
  int kt = c >> 5, g = (c >> 3) & 3, jj = c & 7;
  int u = n * 4 + (g ^ ((n >> 1) & 3));
  int off = kt * 8192 + u * 8 + jj;
  u16 h = f2b(v);
  ph[off] = h;
  pl[off] = f2b(v - b2f(h));
}

// ---------------------------------------------------------------------------
// Kernel 2: ball query + features -> swizzled X planes [24576,256].
// 8 queries/block, 2 waves/query (segments [0,2048)/[2048,4096)).
// Inner scan only RECORDS accepted indices (first-16-by-index via ballot
// prefix); stats computed once over the merged <=16 list.
// ---------------------------------------------------------------------------
__global__ __launch_bounds__(1024) void feat_kernel(
    const float* __restrict__ points, const float* __restrict__ normals,
    const float* __restrict__ parts, const float* __restrict__ rays,
    const float* __restrict__ ro,
    u16* __restrict__ Xh, u16* __restrict__ Xl)
{
  __shared__ float2 pxy[4096];          // 32 KB
  __shared__ float  pzs[4096];          // 16 KB
  __shared__ u16    hl[8][2][16];
  __shared__ int    hn[8][2];
  __shared__ float  sdata[8][20];

  const int tid = threadIdx.x;
  #pragma unroll
  for (int s = 0; s < 4; ++s) {
    int j = tid + s * 1024;
    pxy[j] = make_float2(parts[3 * j + 0], parts[3 * j + 1]);
    pzs[j] = parts[3 * j + 2];
  }
  __syncthreads();

  const int lane = tid & 63, wv = tid >> 6;
  const int qi = wv >> 1, sg = wv & 1;
  const int q = blockIdx.x * 8 + qi;
  const float qx = points[3 * q], qy = points[3 * q + 1], qz = points[3 * q + 2];
  const float RQ = 0.1f * 0.1f;

  int total = 0;
  const int jbase = sg * 2048;
  for (int jr = 0; jr < 32; ++jr) {
    int idx = jbase + jr * 64 + lane;
    float2 xy = pxy[idx];
    float z = pzs[idx];
    float ex = xy.x - qx, ey = xy.y - qy, ez = z - qz;
    float d2 = __fadd_rn(__fadd_rn(__fmul_rn(ex, ex), __fmul_rn(ey, ey)), __fmul_rn(ez, ez));
    bool hit = d2 < RQ;
    unsigned long long m = __ballot(hit);
    int pos = __builtin_amdgcn_mbcnt_hi((unsigned)(m >> 32),
              __builtin_amdgcn_mbcnt_lo((unsigned)m, 0u));
    if (hit && (total + pos < 16)) hl[qi][sg][total + pos] = (u16)idx;
    total += __popcll(m);
    if (total >= 16) break;
  }
  if (lane == 0) hn[qi][sg] = (total < 16) ? total : 16;
  __syncthreads();

  if (sg == 0) {
    const int nA = hn[qi][0];
    const int nB = hn[qi][1];
    int n = nA + nB; n = (n < 16) ? n : 16;

    float cnt = 0, sdx = 0, sdy = 0, sdz = 0, s2x = 0, s2y = 0, s2z = 0;
    float sw = 0, swx = 0, swy = 0, swz = 0;
    if (lane < n) {
      int p = (lane < nA) ? hl[qi][0][lane] : hl[qi][1][lane - nA];
      float2 xy = pxy[p];
      float pz = pzs[p];
      float ex = xy.x - qx, ey = xy.y - qy, ez = pz - qz;
      cnt = 1.0f;
      sdx = ex; sdy = ey; sdz = ez;
      s2x = ex * ex; s2y = ey * ey; s2z = ez * ez;
      float d2 = ex * ex + ey * ey + ez * ez;
      float dn = sqrtf(d2);
      float t = dn * 10.0f;
      sw = fmaxf(1.0f - t * t * t, 0.0f);
      swx = sw * xy.x; swy = sw * xy.y; swz = sw * pz;
    }
    #define WRED(x) { _Pragma("unroll") for (int o = 32; o; o >>= 1) x += __shfl_xor(x, o, 64); }
    WRED(cnt); WRED(sdx); WRED(sdy); WRED(sdz);
    WRED(s2x); WRED(s2y); WRED(s2z);
    WRED(sw); WRED(swx); WRED(swy); WRED(swz);
    #undef WRED

    float fn = cnt;
    float tq = sqrtf(qx * qx + qy * qy + qz * qz) * 10.0f;
    float wpad = fmaxf(1.0f - tq * tq * tq, 0.0f);
    float density = sw + (16.0f - fn) * wpad;
    float invd = 1.0f / (density + 1e-12f);
    float spx = swx * invd, spy = swy * invd, spz = swz * invd;

    float invn = 1.0f / (fn + 1e-12f);
    float mx = sdx * invn, my = sdy * invn, mz = sdz * invn;
    float vx = fmaxf((s2x - 2.0f * mx * sdx + fn * mx * mx) * invn, 0.0f);
    float vy = fmaxf((s2y - 2.0f * my * sdy + fn * my * my) * invn, 0.0f);
    float vz = fmaxf((s2z - 2.0f * mz * sdz + fn * mz * mz) * invn, 0.0f);

    float dxx = spx - ro[0], dyy = spy - ro[1], dzz = spz - ro[2];
    float il = 1.0f / sqrtf(dxx * dxx + dyy * dyy + dzz * dzz);

    if (lane == 0) {
      float* s = sdata[qi];
      s[0] = qx; s[1] = qy; s[2] = qz; s[3] = density;
      s[4] = spx; s[5] = spy; s[6] = spz;
      s[7] = vx; s[8] = vy; s[9] = vz;
      int r = q / 48;
      s[10] = rays[6 * r + 3]; s[11] = rays[6 * r + 4]; s[12] = rays[6 * r + 5];
      s[13] = dxx * il; s[14] = dyy * il; s[15] = dzz * il;
      s[16] = normals[3 * q]; s[17] = normals[3 * q + 1]; s[18] = normals[3 * q + 2];
    }
  }
  __syncthreads();

  // posenc: 8 queries x 256 cols over 1024 threads -> 2 cols/thread
  {
    const int pqi = tid >> 7;
    const int pq = blockIdx.x * 8 + pqi;
    const float* s = sdata[pqi];
    const int b = pq / 96, m = pq % 96;
    const size_t base = (size_t)b * 24576;
    #pragma unroll
    for (int it = 0; it < 2; ++it) {
      int c = (tid & 127) + it * 128;
      int e = ftab.v[c];
      float sv = s[e & 31];
      float arg = sv * (float)(1 << ((e >> 5) & 15));
      float sn, cs;
      sincosf(arg, &sn, &cs);
      int kind = e >> 9;
      float val = (kind == 0) ? sv : (kind == 1 ? sn : (kind == 2 ? cs : 0.0f));
      u16 h = f2b(val);
      int kt = c >> 5, g = (c >> 3) & 3, j = c & 7;
      int u = m * 4 + (g ^ ((m >> 1) & 3));
      size_t off = base + kt * 3072 + u * 8 + j;
      Xh[off] = h;
      Xl[off] = f2b(val - b2f(h));
    }
  }
}

// ---------------------------------------------------------------------------
// Kernel 3: fused 3-layer split-bf16 MFMA MLP + final 256->3 + sigmoid.
// 256 blocks x 768 thr (12 waves, 3x4 wave grid, wave tile 32x64),
// 96 rows/block, 160 KB LDS, 1 block/CU. Double-buffered B (and A in L0)
// staging: stage(kt+1) issued before compute(kt), so the barrier drain
// waits on loads that had a full compute phase in flight.
// LDS: Hh [0,48K) Hl [48K,96K) | B dbuf 4x16K [96K,160K).
// L0 A-stage dbuf aliases H[0,24K); w3s aliases B in final phase.
// ---------------------------------------------------------------------------
__global__ __launch_bounds__(768) void fused_mlp(
    const u16* __restrict__ Xh, const u16* __restrict__ Xl,
    const float* __restrict__ fvec,
    const u16* __restrict__ w0h, const u16* __restrict__ w0l,
    const u16* __restrict__ w1h, const u16* __restrict__ w1l,
    const u16* __restrict__ w2h, const u16* __restrict__ w2l,
    const float* __restrict__ b0, const float* __restrict__ b1,
    const float* __restrict__ b2,
    const float* __restrict__ W3, const float* __restrict__ b3,
    float* __restrict__ out)
{
  extern __shared__ char lds[];
  u16* Hh  = (u16*)lds;                    // 49152 B
  u16* Hl  = (u16*)(lds + 49152);          // 49152 B
  u16* Bh0 = (u16*)(lds + 98304);          // 16384 B each
  u16* Bl0 = (u16*)(lds + 114688);
  u16* Bh1 = (u16*)(lds + 131072);
  u16* Bl1 = (u16*)(lds + 147456);
  u16* Ah0 = (u16*)lds;                    // 6144 B each (alias H, L0 only)
  u16* Al0 = (u16*)(lds + 6144);
  u16* Ah1 = (u16*)(lds + 12288);
  u16* Al1 = (u16*)(lds + 18432);
  float* w3s = (float*)(lds + 98304);      // final phase

  const int tid = threadIdx.x, lane = tid & 63, wv = tid >> 6;
  const int wm = wv >> 2, wn = wv & 3;     // 3 x 4
  const int l15 = lane & 15, l4 = lane >> 4;
  const int blk = blockIdx.x;

  f32x4 acc[2][4];

  auto stageB = [&](const u16* wh_, const u16* wl_, int kt, int p) {
    u16* bh = p ? Bh1 : Bh0;
    u16* bl = p ? Bl1 : Bl0;
    #pragma unroll
    for (int s = 0; s < 3; ++s) {
      int ch = wv + s * 12;
      if (ch < 32) {
        const u16* src = (ch < 16) ? (wh_ + kt * 8192 + ch * 512)
                                   : (wl_ + kt * 8192 + (ch - 16) * 512);
        u16* dst = (ch < 16) ? (bh + ch * 512) : (bl + (ch - 16) * 512);
        glds16(src + lane * 8, dst + lane * 8);
      }
    }
  };
  auto stageA = [&](int kt, int p) {
    if (kt < 8) {
      const u16* src = (wv < 6) ? (Xh + (size_t)blk * 24576 + kt * 3072 + wv * 512)
                                : (Xl + (size_t)blk * 24576 + kt * 3072 + (wv - 6) * 512);
      u16* dst = (wv < 6) ? ((p ? Ah1 : Ah0) + wv * 512)
                          : ((p ? Al1 : Al0) + (wv - 6) * 512);
      glds16(src + lane * 8, dst + lane * 8);
    } else {
      int m = tid >> 3, j8 = tid & 7;
      const float* src = fvec + (size_t)(blk * 96 + m) * 256 + (kt - 8) * 32 + j8 * 4;
      float4 v = *(const float4*)src;
      float vv[4] = {v.x, v.y, v.z, v.w};
      u16 hs[4], ls[4];
      #pragma unroll
      for (int s = 0; s < 4; ++s) {
        hs[s] = f2b(vv[s]);
        ls[s] = f2b(vv[s] - b2f(hs[s]));
      }
      int u = m * 4 + ((j8 >> 1) ^ ((m >> 1) & 3));
      int off = u * 8 + (j8 & 1) * 4;
      *(uint2*)((p ? Ah1 : Ah0) + off) = *(uint2*)hs;
      *(uint2*)((p ? Al1 : Al0) + off) = *(uint2*)ls;
    }
  };
  auto bfrags = [&](int p, bf16x8* bh, bf16x8* bl) {
    const u16* Bsh = p ? Bh1 : Bh0;
    const u16* Bsl = p ? Bl1 : Bl0;
    #pragma unroll
    for (int j = 0; j < 4; ++j) {
      int n = wn * 64 + j * 16 + l15;
      int u = n * 4 + (l4 ^ ((n >> 1) & 3));
      bh[j] = __builtin_bit_cast(bf16x8, *(const uint4*)(Bsh + u * 8));
      bl[j] = __builtin_bit_cast(bf16x8, *(const uint4*)(Bsl + u * 8));
    }
  };
  auto mfmas = [&](bf16x8* ah, bf16x8* al, bf16x8* bh, bf16x8* bl) {
    #pragma unroll
    for (int i = 0; i < 2; ++i)
      #pragma unroll
      for (int j = 0; j < 4; ++j) {
        acc[i][j] = __builtin_amdgcn_mfma_f32_16x16x32_bf16(ah[i], bh[j], acc[i][j], 0, 0, 0);
        acc[i][j] = __builtin_amdgcn_mfma_f32_16x16x32_bf16(ah[i], bl[j], acc[i][j], 0, 0, 0);
        acc[i][j] = __builtin_amdgcn_mfma_f32_16x16x32_bf16(al[i], bh[j], acc[i][j], 0, 0, 0);
      }
  };
  auto epilogue = [&](const float* bias_) {
    float bv[4];
    #pragma unroll
    for (int j = 0; j < 4; ++j) bv[j] = bias_[wn * 64 + j * 16 + l15];
    #pragma unroll
    for (int i = 0; i < 2; ++i) {
      #pragma unroll
      for (int r = 0; r < 4; ++r) {
        int m = wm * 32 + i * 16 + l4 * 4 + r;
        #pragma unroll
        for (int j = 0; j < 4; ++j) {
          int n = wn * 64 + j * 16 + l15;
          float v = fmaxf(acc[i][j][r] + bv[j], 0.0f);
          u16 h = f2b(v);
          int u = m * 32 + ((n >> 3) ^ ((m >> 1) & 7));
          int off = u * 8 + (n & 7);
          Hh[off] = h;
          Hl[off] = f2b(v - b2f(h));
        }
      }
    }
  };

  // ======================= L0: K=512 (8 kt from X, 8 from fvec) ============
  #pragma unroll
  for (int i = 0; i < 2; ++i)
    #pragma unroll
    for (int j = 0; j < 4; ++j) acc[i][j] = (f32x4){0, 0, 0, 0};

  stageA(0, 0);
  stageB(w0h, w0l, 0, 0);
  int par = 0;
  for (int kt = 0; kt < 16; ++kt) {
    __syncthreads();
    if (kt + 1 < 16) {
      stageA(kt + 1, par ^ 1);
      stageB(w0h, w0l, kt + 1, par ^ 1);
    }
    bf16x8 ah[2], al[2], bh[4], bl[4];
    const u16* Ash = par ? Ah1 : Ah0;
    const u16* Asl = par ? Al1 : Al0;
    #pragma unroll
    for (int i = 0; i < 2; ++i) {
      int m = wm * 32 + i * 16 + l15;
      int u = m * 4 + (l4 ^ ((m >> 1) & 3));
      ah[i] = __builtin_bit_cast(bf16x8, *(const uint4*)(Ash + u * 8));
      al[i] = __builtin_bit_cast(bf16x8, *(const uint4*)(Asl + u * 8));
    }
    bfrags(par, bh, bl);
    mfmas(ah, al, bh, bl);
    par ^= 1;
  }
  __syncthreads();
  epilogue(b0);

  // ======================= L1, L2: K=256, A from H =========================
  #pragma unroll 1
  for (int layer = 0; layer < 2; ++layer) {
    const u16* wh_ = layer ? w2h : w1h;
    const u16* wl_ = layer ? w2l : w1l;
    #pragma unroll
    for (int i = 0; i < 2; ++i)
      #pragma unroll
      for (int j = 0; j < 4; ++j) acc[i][j] = (f32x4){0, 0, 0, 0};

    stageB(wh_, wl_, 0, 0);
    par = 0;
    for (int kt = 0; kt < 8; ++kt) {
      __syncthreads();
      if (kt + 1 < 8) stageB(wh_, wl_, kt + 1, par ^ 1);
      bf16x8 ah[2], al[2], bh[4], bl[4];
      #pragma unroll
      for (int i = 0; i < 2; ++i) {
        int m = wm * 32 + i * 16 + l15;
        int g = kt * 4 + l4;
        int u = m * 32 + (g ^ ((m >> 1) & 7));
        ah[i] = __builtin_bit_cast(bf16x8, *(const uint4*)(Hh + u * 8));
        al[i] = __builtin_bit_cast(bf16x8, *(const uint4*)(Hl + u * 8));
      }
      bfrags(par, bh, bl);
      mfmas(ah, al, bh, bl);
      par ^= 1;
    }
    __syncthreads();
    epilogue(layer ? b2 : b1);
  }

  // ======================= final: 256 -> 3 + sigmoid =======================
  for (int i = tid; i < 768; i += 768) w3s[i] = W3[i];
  __syncthreads();

  const float B30 = b3[0], B31 = b3[1], B32 = b3[2];
  #pragma unroll 1
  for (int rr = 0; rr < 8; ++rr) {
    int m = wv * 8 + rr;
    int g = lane >> 1, j0 = (lane & 1) * 4;
    int u = m * 32 + (g ^ ((m >> 1) & 7));
    uint2 ph_ = *(const uint2*)(Hh + u * 8 + j0);
    uint2 pl_ = *(const uint2*)(Hl + u * 8 + j0);
    float h0 = b2f((u16)(ph_.x & 0xffff)) + b2f((u16)(pl_.x & 0xffff));
    float h1 = b2f((u16)(ph_.x >> 16))    + b2f((u16)(pl_.x >> 16));
    float h2 = b2f((u16)(ph_.y & 0xffff)) + b2f((u16)(pl_.y & 0xffff));
    float h3 = b2f((u16)(ph_.y >> 16))    + b2f((u16)(pl_.y >> 16));
    int kc = lane * 4;
    float4 wa = *(const float4*)(w3s + kc);
    float4 wb = *(const float4*)(w3s + 256 + kc);
    float4 wc = *(const float4*)(w3s + 512 + kc);
    float p0 = fmaf(h3, wa.w, fmaf(h2, wa.z, fmaf(h1, wa.y, h0 * wa.x)));
    float p1 = fmaf(h3, wb.w, fmaf(h2, wb.z, fmaf(h1, wb.y, h0 * wb.x)));
    float p2 = fmaf(h3, wc.w, fmaf(h2, wc.z, fmaf(h1, wc.y, h0 * wc.x)));
    #pragma unroll
    for (int o = 32; o; o >>= 1) {
      p0 += __shfl_xor(p0, o, 64);
      p1 += __shfl_xor(p1, o, 64);
      p2 += __shfl_xor(p2, o, 64);
    }
    if (lane == 0) {
      size_t ro_ = (size_t)(blk * 96 + m) * 3;
      out[ro_ + 0] = 1.0f / (1.0f + expf(-(p0 + B30)));
      out[ro_ + 1] = 1.0f / (1.0f + expf(-(p1 + B31)));
      out[ro_ + 2] = 1.0f / (1.0f + expf(-(p2 + B32)));
    }
  }
}

// ---------------------------------------------------------------------------
extern "C" void kernel_launch(void* const* d_in, const int* in_sizes, int n_in,
                              void* d_out, int out_size, void* d_ws, size_t ws_size,
                              hipStream_t stream) {
  const float* points  = (const float*)d_in[0];
  const float* normals = (const float*)d_in[1];
  const float* fvec    = (const float*)d_in[3];
  const float* parts   = (const float*)d_in[5];
  const float* rays    = (const float*)d_in[6];
  const float* ro      = (const float*)d_in[7];
  const float* W0 = (const float*)d_in[8];
  const float* b0 = (const float*)d_in[9];
  const float* W1 = (const float*)d_in[10];
  const float* b1 = (const float*)d_in[11];
  const float* W2 = (const float*)d_in[12];
  const float* b2 = (const float*)d_in[13];
  const float* W3 = (const float*)d_in[14];
  const float* b3 = (const float*)d_in[15];

  char* ws = (char*)d_ws;
  u16* Xh  = (u16*)(ws);                     // [24576,256] swizzled, 12.58 MB
  u16* Xl  = (u16*)(ws + 12582912);
  u16* w0h = (u16*)(ws + 25165824);          // 262144 B
  u16* w0l = (u16*)(ws + 25427968);
  u16* w1h = (u16*)(ws + 25690112);          // 131072 B
  u16* w1l = (u16*)(ws + 25821184);
  u16* w2h = (u16*)(ws + 25952256);
  u16* w2l = (u16*)(ws + 26083328);
  float* out = (float*)d_out;

  (void)hipFuncSetAttribute((const void*)fused_mlp,
                            hipFuncAttributeMaxDynamicSharedMemorySize, 163840);

  prep_weights<<<1024, 256, 0, stream>>>(W0, W1, W2, w0h, w0l, w1h, w1l, w2h, w2l);
  feat_kernel<<<3072, 1024, 0, stream>>>(points, normals, parts, rays, ro, Xh, Xl);
  fused_mlp<<<256, 768, 163840, stream>>>(Xh, Xl, fvec, w0h, w0l, w1h, w1l, w2h, w2l,
                                          b0, b1, b2, W3, b3, out);
}

// Round 8
// 212.877 us; speedup vs baseline: 1.2580x; 1.2580x over previous
//
#include <hip/hip_runtime.h>

typedef __bf16 bf16x8 __attribute__((ext_vector_type(8)));
typedef float f32x4 __attribute__((ext_vector_type(4)));
typedef unsigned short u16;

__device__ __forceinline__ u16 f2b(float f) {
  unsigned u = __builtin_bit_cast(unsigned, f);
  u = (u + 0x7FFFu + ((u >> 16) & 1u)) >> 16;
  return (u16)u;
}
__device__ __forceinline__ float b2f(u16 h) {
  return __builtin_bit_cast(float, (unsigned)h << 16);
}

// async global->LDS, 16B per lane. dst = wave-uniform base + lane*16.
__device__ __forceinline__ void glds16(const u16* g, u16* l) {
  __builtin_amdgcn_global_load_lds(
      (const __attribute__((address_space(1))) unsigned*)g,
      (__attribute__((address_space(3))) unsigned*)l, 16, 0, 0);
}

// ---------------------------------------------------------------------------
// Swizzled layouts (16B = 8-u16 units, BK=32 K-tiles), M-block = 48 rows:
// X [24576,256]: q -> b=q/48, m=q%48; c -> kt=c>>5, g=(c>>3)&3, j=c&7;
//   u = m*4 + (g ^ ((m>>1)&3));  elem off = b*12288 + kt*1536 + u*8 + j
// W [256,K]: n,c -> kt=c>>5, g=(c>>3)&3, j=c&7; u = n*4 + (g^((n>>1)&3));
//   off = kt*8192 + u*8 + j
// H (LDS, 48x256): m,k -> g=k>>3; u = m*32 + (g ^ ((m>>1)&7))
// ---------------------------------------------------------------------------

// ---------------------------------------------------------------------------
// Column decode table: col -> (src scalar idx, freq, kind)
// kind: 0 raw, 1 sin, 2 cos, 3 zero.  enc = src | f<<5 | kind<<9
// ---------------------------------------------------------------------------
struct FT {
  u16 v[256];
  static constexpr u16 enc(int s, int f, int k) {
    return (u16)(s | (f << 5) | (k << 9));
  }
  constexpr void p3(int base, int F, int src) {
    v[base + 0] = enc(src + 0, 0, 0);
    v[base + 1] = enc(src + 1, 0, 0);
    v[base + 2] = enc(src + 2, 0, 0);
    for (int f = 0; f < F; ++f)
      for (int r = 0; r < 6; ++r) {
        int comp = (r < 3) ? r : r - 3;
        v[base + 3 + f * 6 + r] = enc(src + comp, f, (r < 3) ? 1 : 2);
      }
  }
  constexpr void p1(int base, int F, int src) {
    v[base] = enc(src, 0, 0);
    for (int f = 0; f < F; ++f) {
      v[base + 1 + 2 * f] = enc(src, f, 1);
      v[base + 2 + 2 * f] = enc(src, f, 2);
    }
  }
  constexpr FT() : v{} {
    p3(0, 10, 0);     // hit_pos_emb   (q)          [0..62]
    p1(63, 4, 3);     // density_emb                [63..71]
    p3(72, 10, 4);    // smoothed_emb  (sp)         [72..134]
    p3(135, 10, 7);   // var_emb       (var)        [135..197]
    p3(198, 4, 10);   // hit_dir_emb   (ray dir)    [198..224]
    p3(225, 4, 13);   // dirs_emb      (dir)        [225..251]
    v[252] = enc(16, 0, 0);  // normals
    v[253] = enc(17, 0, 0);
    v[254] = enc(18, 0, 0);
    v[255] = enc(0, 0, 3);   // pad col
  }
};
__constant__ FT ftab = FT();

// ---------------------------------------------------------------------------
// Kernel 1: weight prep fp32 -> split bf16 planes, BK=32 swizzled layout.
// W0 [256,511] -> [256,512]: col 255 = 0, cols 256..511 = orig 255..510.
// ---------------------------------------------------------------------------
__global__ __launch_bounds__(256) void prep_weights(
    const float* __restrict__ W0, const float* __restrict__ W1,
    const float* __restrict__ W2,
    u16* __restrict__ w0h, u16* __restrict__ w0l,
    u16* __restrict__ w1h, u16* __restrict__ w1l,
    u16* __restrict__ w2h, u16* __restrict__ w2l)
{
  int i = blockIdx.x * 256 + threadIdx.x;   // 0 .. 262143
  float v; u16 *ph, *pl; int n, c;
  if (i < 131072) {
    n = i >> 9; c = i & 511;
    v = (c < 255) ? W0[n * 511 + c] : ((c == 255) ? 0.0f : W0[n * 511 + (c - 1)]);
    ph = w0h; pl = w0l;
  } else if (i < 196608) {
    int j = i - 131072; n = j >> 8; c = j & 255; v = W1[j]; ph = w1h; pl = w1l;
  } else {
    int j = i - 196608; n = j >> 8; c = j & 255; v = W2[j]; ph = w2h; pl = w2l;
  }
  int kt = c >> 5, g = (c >> 3) & 3, jj = c & 7;
  int u = n * 4 + (g ^ ((n >> 1) & 3));
  int off = kt * 8192 + u * 8 + jj;
  u16 h = f2b(v);
  ph[off] = h;
  pl[off] = f2b(v - b2f(h));
}

// ---------------------------------------------------------------------------
// Kernel 2: ball query + features -> swizzled X planes [24576,256].
// 1 wave/query, 16 queries/block. Lane i tests particle j*64+i; the scan
// only RECORDS accepted indices (first-16-by-index via ballot prefix,
// wave-uniform early break); stats computed once over the <=16 hits.
// ---------------------------------------------------------------------------
__global__ __launch_bounds__(1024) void feat_kernel(
    const float* __restrict__ points, const float* __restrict__ normals,
    const float* __restrict__ parts, const float* __restrict__ rays,
    const float* __restrict__ ro,
    u16* __restrict__ Xh, u16* __restrict__ Xl)
{
  __shared__ float2 pxy[4096];          // 32 KB
  __shared__ float  pzs[4096];          // 16 KB
  __shared__ u16    hlist[16][16];
  __shared__ float  sdata[16][20];

  const int tid = threadIdx.x;
  for (int j = tid; j < 4096; j += 1024) {
    pxy[j] = make_float2(parts[3 * j + 0], parts[3 * j + 1]);
    pzs[j] = parts[3 * j + 2];
  }
  __syncthreads();

  const int lane = tid & 63, wv = tid >> 6;
  const int q = blockIdx.x * 16 + wv;
  const float qx = points[3 * q], qy = points[3 * q + 1], qz = points[3 * q + 2];
  const float RQ = 0.1f * 0.1f;

  int total = 0;
  for (int jr = 0; jr < 64; ++jr) {
    int idx = jr * 64 + lane;
    float2 xy = pxy[idx];
    float z = pzs[idx];
    float ex = xy.x - qx, ey = xy.y - qy, ez = z - qz;
    float d2 = __fadd_rn(__fadd_rn(__fmul_rn(ex, ex), __fmul_rn(ey, ey)), __fmul_rn(ez, ez));
    bool hit = d2 < RQ;
    unsigned long long m = __ballot(hit);
    if (hit) {
      int slot = total + __builtin_amdgcn_mbcnt_hi((unsigned)(m >> 32),
                 __builtin_amdgcn_mbcnt_lo((unsigned)m, 0u));
      if (slot < 16) hlist[wv][slot] = (u16)idx;
    }
    total += __popcll(m);
    if (total >= 16) break;     // wave-uniform
  }
  __syncthreads();

  const int n = (total < 16) ? total : 16;
  float cnt = 0, sdx = 0, sdy = 0, sdz = 0, s2x = 0, s2y = 0, s2z = 0;
  float sw = 0, swx = 0, swy = 0, swz = 0;
  if (lane < n) {
    int p = hlist[wv][lane];
    float2 xy = pxy[p];
    float pz = pzs[p];
    float ex = xy.x - qx, ey = xy.y - qy, ez = pz - qz;
    cnt = 1.0f;
    sdx = ex; sdy = ey; sdz = ez;
    s2x = ex * ex; s2y = ey * ey; s2z = ez * ez;
    float d2 = ex * ex + ey * ey + ez * ez;
    float dn = sqrtf(d2);
    float t = dn * 10.0f;
    sw = fmaxf(1.0f - t * t * t, 0.0f);
    swx = sw * xy.x; swy = sw * xy.y; swz = sw * pz;
  }
  #define WRED(x) { _Pragma("unroll") for (int o = 32; o; o >>= 1) x += __shfl_xor(x, o, 64); }
  WRED(cnt); WRED(sdx); WRED(sdy); WRED(sdz);
  WRED(s2x); WRED(s2y); WRED(s2z);
  WRED(sw); WRED(swx); WRED(swy); WRED(swz);
  #undef WRED

  float fn = cnt;
  float tq = sqrtf(qx * qx + qy * qy + qz * qz) * 10.0f;
  float wpad = fmaxf(1.0f - tq * tq * tq, 0.0f);
  float density = sw + (16.0f - fn) * wpad;
  float invd = 1.0f / (density + 1e-12f);
  float spx = swx * invd, spy = swy * invd, spz = swz * invd;

  float invn = 1.0f / (fn + 1e-12f);
  float mx = sdx * invn, my = sdy * invn, mz = sdz * invn;
  float vx = fmaxf((s2x - 2.0f * mx * sdx + fn * mx * mx) * invn, 0.0f);
  float vy = fmaxf((s2y - 2.0f * my * sdy + fn * my * my) * invn, 0.0f);
  float vz = fmaxf((s2z - 2.0f * mz * sdz + fn * mz * mz) * invn, 0.0f);

  float dxx = spx - ro[0], dyy = spy - ro[1], dzz = spz - ro[2];
  float il = 1.0f / sqrtf(dxx * dxx + dyy * dyy + dzz * dzz);

  if (lane == 0) {
    float* s = sdata[wv];
    s[0] = qx; s[1] = qy; s[2] = qz; s[3] = density;
    s[4] = spx; s[5] = spy; s[6] = spz;
    s[7] = vx; s[8] = vy; s[9] = vz;
    int r = q / 48;
    s[10] = rays[6 * r + 3]; s[11] = rays[6 * r + 4]; s[12] = rays[6 * r + 5];
    s[13] = dxx * il; s[14] = dyy * il; s[15] = dzz * il;
    s[16] = normals[3 * q]; s[17] = normals[3 * q + 1]; s[18] = normals[3 * q + 2];
  }
  __syncthreads();

  const int b = q / 48, m96 = q % 48;
  const size_t base = (size_t)b * 12288;
  #pragma unroll
  for (int it = 0; it < 4; ++it) {
    int c = it * 64 + lane;
    int e = ftab.v[c];
    float sv = sdata[wv][e & 31];
    float arg = sv * (float)(1 << ((e >> 5) & 15));
    float sn, cs;
    sincosf(arg, &sn, &cs);
    int kind = e >> 9;
    float val = (kind == 0) ? sv : (kind == 1 ? sn : (kind == 2 ? cs : 0.0f));
    u16 h = f2b(val);
    int kt = c >> 5, g = (c >> 3) & 3, j = c & 7;
    int u = m96 * 4 + (g ^ ((m96 >> 1) & 3));
    size_t off = base + kt * 1536 + u * 8 + j;
    Xh[off] = h;
    Xl[off] = f2b(val - b2f(h));
  }
}

// ---------------------------------------------------------------------------
// Kernel 3: fused 3-layer split-bf16 MFMA MLP + final 256->3 + sigmoid.
// 512 blocks x 256 thr (4 waves, wave tile 48x64), 48 rows/block, 80 KB LDS
// -> 2 blocks/CU. K-loop reordered: drain-barrier -> frag reads into regs ->
// barrier -> stage(kt+1) glds -> MFMA(kt) (stage flies under the MFMA burst).
// Odd blocks sleep ~512 cyc at start to de-phase the two co-resident blocks.
// ---------------------------------------------------------------------------
__global__ __launch_bounds__(256, 2) void fused_mlp(
    const u16* __restrict__ Xh, const u16* __restrict__ Xl,
    const float* __restrict__ fvec,
    const u16* __restrict__ w0h, const u16* __restrict__ w0l,
    const u16* __restrict__ w1h, const u16* __restrict__ w1l,
    const u16* __restrict__ w2h, const u16* __restrict__ w2l,
    const float* __restrict__ b0, const float* __restrict__ b1,
    const float* __restrict__ b2,
    const float* __restrict__ W3, const float* __restrict__ b3,
    float* __restrict__ out)
{
  extern __shared__ char lds[];
  u16* Hh    = (u16*)lds;
  u16* Hl    = (u16*)(lds + 24576);
  u16* Bsh   = (u16*)(lds + 49152);
  u16* Bsl   = (u16*)(lds + 65536);
  u16* Ah_st = (u16*)lds;              // 3072 B (L0 only, aliases Hh)
  u16* Al_st = (u16*)(lds + 3072);
  float* w3s = (float*)(lds + 49152);

  const int tid = threadIdx.x, lane = tid & 63, wn = tid >> 6;
  const int l15 = lane & 15, l4 = lane >> 4;
  const int blk = blockIdx.x;

  if (blk & 1) __builtin_amdgcn_s_sleep(8);   // ~512 cyc stagger

  f32x4 acc[3][4];

  const u16* Xht = Xh + (size_t)blk * 12288;
  const u16* Xlt = Xl + (size_t)blk * 12288;

  auto stageB = [&](const u16* wh_, const u16* wl_, int kt) {
    #pragma unroll
    for (int s = 0; s < 8; ++s) {
      int ch = wn + s * 4;
      const u16* bs = (ch < 16) ? (wh_ + kt * 8192 + ch * 512)
                                : (wl_ + kt * 8192 + (ch - 16) * 512);
      u16* bd = (ch < 16) ? (Bsh + ch * 512) : (Bsl + (ch - 16) * 512);
      glds16(bs + lane * 8, bd + lane * 8);
    }
  };
  auto stageA = [&](int kt) {
    if (kt < 8) {
      const u16* s0; u16* d0;
      if (wn < 3) { s0 = Xht + kt * 1536 + wn * 512; d0 = Ah_st + wn * 512; }
      else        { s0 = Xlt + kt * 1536;            d0 = Al_st; }
      glds16(s0 + lane * 8, d0 + lane * 8);
      if (wn < 2)
        glds16(Xlt + kt * 1536 + (wn + 1) * 512 + lane * 8,
               Al_st + (wn + 1) * 512 + lane * 8);
    } else {
      if (tid < 192) {
        int m = tid >> 2, g = tid & 3;
        const float* src = fvec + (size_t)(blk * 48 + m) * 256 + (kt - 8) * 32 + g * 8;
        float4 v0 = ((const float4*)src)[0];
        float4 v1 = ((const float4*)src)[1];
        float vv[8] = {v0.x, v0.y, v0.z, v0.w, v1.x, v1.y, v1.z, v1.w};
        u16 hs[8], ls[8];
        #pragma unroll
        for (int s = 0; s < 8; ++s) {
          hs[s] = f2b(vv[s]);
          ls[s] = f2b(vv[s] - b2f(hs[s]));
        }
        int u = m * 4 + (g ^ ((m >> 1) & 3));
        *(uint4*)(Ah_st + u * 8) = *(uint4*)hs;
        *(uint4*)(Al_st + u * 8) = *(uint4*)ls;
      }
    }
  };
  auto bfrags = [&](bf16x8* bh, bf16x8* bl) {
    #pragma unroll
    for (int j = 0; j < 4; ++j) {
      int n = wn * 64 + j * 16 + l15;
      int u = n * 4 + (l4 ^ ((n >> 1) & 3));
      bh[j] = __builtin_bit_cast(bf16x8, *(const uint4*)(Bsh + u * 8));
      bl[j] = __builtin_bit_cast(bf16x8, *(const uint4*)(Bsl + u * 8));
    }
  };
  auto mfmas = [&](bf16x8* ah, bf16x8* al, bf16x8* bh, bf16x8* bl) {
    #pragma unroll
    for (int i = 0; i < 3; ++i)
      #pragma unroll
      for (int j = 0; j < 4; ++j) {
        acc[i][j] = __builtin_amdgcn_mfma_f32_16x16x32_bf16(ah[i], bh[j], acc[i][j], 0, 0, 0);
        acc[i][j] = __builtin_amdgcn_mfma_f32_16x16x32_bf16(ah[i], bl[j], acc[i][j], 0, 0, 0);
        acc[i][j] = __builtin_amdgcn_mfma_f32_16x16x32_bf16(al[i], bh[j], acc[i][j], 0, 0, 0);
      }
  };
  auto epilogue = [&](const float* bias_) {
    float bv[4];
    #pragma unroll
    for (int j = 0; j < 4; ++j) bv[j] = bias_[wn * 64 + j * 16 + l15];
    #pragma unroll
    for (int i = 0; i < 3; ++i) {
      #pragma unroll
      for (int r = 0; r < 4; ++r) {
        int m = i * 16 + l4 * 4 + r;
        #pragma unroll
        for (int j = 0; j < 4; ++j) {
          int n = wn * 64 + j * 16 + l15;
          float v = fmaxf(acc[i][j][r] + bv[j], 0.0f);
          u16 h = f2b(v);
          int u = m * 32 + ((n >> 3) ^ ((m >> 1) & 7));
          int off = u * 8 + (n & 7);
          Hh[off] = h;
          Hl[off] = f2b(v - b2f(h));
        }
      }
    }
  };

  // ======================= L0: K=512 (8 kt from X, 8 from fvec) ============
  #pragma unroll
  for (int i = 0; i < 3; ++i)
    #pragma unroll
    for (int j = 0; j < 4; ++j) acc[i][j] = (f32x4){0, 0, 0, 0};

  stageA(0);
  stageB(w0h, w0l, 0);
  for (int kt = 0; kt < 16; ++kt) {
    __syncthreads();                       // drain stage(kt)
    bf16x8 ah[3], al[3], bh[4], bl[4];
    #pragma unroll
    for (int i = 0; i < 3; ++i) {
      int m = i * 16 + l15;
      int u = m * 4 + (l4 ^ ((m >> 1) & 3));
      ah[i] = __builtin_bit_cast(bf16x8, *(const uint4*)(Ah_st + u * 8));
      al[i] = __builtin_bit_cast(bf16x8, *(const uint4*)(Al_st + u * 8));
    }
    bfrags(bh, bl);
    __syncthreads();                       // all reads in regs
    if (kt < 15) { stageA(kt + 1); stageB(w0h, w0l, kt + 1); }
    mfmas(ah, al, bh, bl);
  }
  epilogue(b0);                            // reads drained at last barrier

  // ======================= L1, L2: K=256, A from H =========================
  #pragma unroll 1
  for (int layer = 0; layer < 2; ++layer) {
    const u16* wh_ = layer ? w2h : w1h;
    const u16* wl_ = layer ? w2l : w1l;
    #pragma unroll
    for (int i = 0; i < 3; ++i)
      #pragma unroll
      for (int j = 0; j < 4; ++j) acc[i][j] = (f32x4){0, 0, 0, 0};

    stageB(wh_, wl_, 0);                   // B region dead during epilogue
    for (int kt = 0; kt < 8; ++kt) {
      __syncthreads();                     // kt=0: also fences epilogue H writes
      bf16x8 ah[3], al[3], bh[4], bl[4];
      #pragma unroll
      for (int i = 0; i < 3; ++i) {
        int m = i * 16 + l15;
        int g = kt * 4 + l4;
        int u = m * 32 + (g ^ ((m >> 1) & 7));
        ah[i] = __builtin_bit_cast(bf16x8, *(const uint4*)(Hh + u * 8));
        al[i] = __builtin_bit_cast(bf16x8, *(const uint4*)(Hl + u * 8));
      }
      bfrags(bh, bl);
      __syncthreads();
      if (kt < 7) stageB(wh_, wl_, kt + 1);
      mfmas(ah, al, bh, bl);
    }
    epilogue(layer ? b2 : b1);
  }

  // ======================= final: 256 -> 3 + sigmoid =======================
  __syncthreads();                         // H complete, B region free
  for (int i = tid; i < 768; i += 256) w3s[i] = W3[i];
  __syncthreads();

  const float B30 = b3[0], B31 = b3[1], B32 = b3[2];
  #pragma unroll 1
  for (int rr = 0; rr < 12; ++rr) {
    int m = wn * 12 + rr;
    int g = lane >> 1, j0 = (lane & 1) * 4;
    int u = m * 32 + (g ^ ((m >> 1) & 7));
    uint2 ph_ = *(const uint2*)(Hh + u * 8 + j0);
    uint2 pl_ = *(const uint2*)(Hl + u * 8 + j0);
    float h0 = b2f((u16)(ph_.x & 0xffff)) + b2f((u16)(pl_.x & 0xffff));
    float h1 = b2f((u16)(ph_.x >> 16))    + b2f((u16)(pl_.x >> 16));
    float h2 = b2f((u16)(ph_.y & 0xffff)) + b2f((u16)(pl_.y & 0xffff));
    float h3 = b2f((u16)(ph_.y >> 16))    + b2f((u16)(pl_.y >> 16));
    int kc = lane * 4;
    float4 wa = *(const float4*)(w3s + kc);
    float4 wb = *(const float4*)(w3s + 256 + kc);
    float4 wc = *(const float4*)(w3s + 512 + kc);
    float p0 = fmaf(h3, wa.w, fmaf(h2, wa.z, fmaf(h1, wa.y, h0 * wa.x)));
    float p1 = fmaf(h3, wb.w, fmaf(h2, wb.z, fmaf(h1, wb.y, h0 * wb.x)));
    float p2 = fmaf(h3, wc.w, fmaf(h2, wc.z, fmaf(h1, wc.y, h0 * wc.x)));
    #pragma unroll
    for (int o = 32; o; o >>= 1) {
      p0 += __shfl_xor(p0, o, 64);
      p1 += __shfl_xor(p1, o, 64);
      p2 += __shfl_xor(p2, o, 64);
    }
    if (lane == 0) {
      size_t ro_ = (size_t)(blk * 48 + m) * 3;
      out[ro_ + 0] = 1.0f / (1.0f + expf(-(p0 + B30)));
      out[ro_ + 1] = 1.0f / (1.0f + expf(-(p1 + B31)));
      out[ro_ + 2] = 1.0f / (1.0f + expf(-(p2 + B32)));
    }
  }
}

// ---------------------------------------------------------------------------
extern "C" void kernel_launch(void* const* d_in, const int* in_sizes, int n_in,
                              void* d_out, int out_size, void* d_ws, size_t ws_size,
                              hipStream_t stream) {
  const float* points  = (const float*)d_in[0];
  const float* normals = (const float*)d_in[1];
  const float* fvec    = (const float*)d_in[3];
  const float* parts   = (const float*)d_in[5];
  const float* rays    = (const float*)d_in[6];
  const float* ro      = (const float*)d_in[7];
  const float* W0 = (const float*)d_in[8];
  const float* b0 = (const float*)d_in[9];
  const float* W1 = (const float*)d_in[10];
  const float* b1 = (const float*)d_in[11];
  const float* W2 = (const float*)d_in[12];
  const float* b2 = (const float*)d_in[13];
  const float* W3 = (const float*)d_in[14];
  const float* b3 = (const float*)d_in[15];

  char* ws = (char*)d_ws;
  u16* Xh  = (u16*)(ws);                     // [24576,256] swizzled, 12.58 MB
  u16* Xl  = (u16*)(ws + 12582912);
  u16* w0h = (u16*)(ws + 25165824);          // 262144 B
  u16* w0l = (u16*)(ws + 25427968);
  u16* w1h = (u16*)(ws + 25690112);          // 131072 B
  u16* w1l = (u16*)(ws + 25821184);
  u16* w2h = (u16*)(ws + 25952256);
  u16* w2l = (u16*)(ws + 26083328);
  float* out = (float*)d_out;

  (void)hipFuncSetAttribute((const void*)fused_mlp,
                            hipFuncAttributeMaxDynamicSharedMemorySize, 81920);

  prep_weights<<<1024, 256, 0, stream>>>(W0, W1, W2, w0h, w0l, w1h, w1l, w2h, w2l);
  feat_kernel<<<1536, 1024, 0, stream>>>(points, normals, parts, rays, ro, Xh, Xl);
  fused_mlp<<<512, 256, 81920, stream>>>(Xh, Xl, fvec, w0h, w0l, w1h, w1l, w2h, w2l,
                                         b0, b1, b2, W3, b3, out);
}

// Round 9
// 193.462 us; speedup vs baseline: 1.3842x; 1.1004x over previous
//
#include <hip/hip_runtime.h>

typedef _Float16 f16;
typedef f16 f16x8 __attribute__((ext_vector_type(8)));
typedef float f32x4 __attribute__((ext_vector_type(4)));
typedef unsigned short u16;

// async global->LDS, 16B per lane. dst = wave-uniform base + lane*16.
__device__ __forceinline__ void glds16(const void* g, void* l) {
  __builtin_amdgcn_global_load_lds(
      (const __attribute__((address_space(1))) unsigned*)g,
      (__attribute__((address_space(3))) unsigned*)l, 16, 0, 0);
}

// ---------------------------------------------------------------------------
// Swizzled fp16 layouts (16B = 8-f16 units, BK=32 K-tiles), M-block = 48:
// X [24576,256]: q -> b=q/48, m=q%48; c -> kt=c>>5, g=(c>>3)&3, j=c&7;
//   u = m*4 + (g ^ ((m>>1)&3));  elem off = b*12288 + kt*1536 + u*8 + j
// W [256,K]: n,c -> kt=c>>5, g=(c>>3)&3, j=c&7; u = n*4 + (g^((n>>1)&3));
//   off = kt*8192 + u*8 + j
// H (LDS, 48x256): m,k -> g=k>>3; u = m*32 + (g ^ ((m>>1)&7))
// ---------------------------------------------------------------------------

// ---------------------------------------------------------------------------
// Column decode table: col -> (src scalar idx, freq, kind)
// kind: 0 raw, 1 sin, 2 cos, 3 zero.  enc = src | f<<5 | kind<<9
// ---------------------------------------------------------------------------
struct FT {
  u16 v[256];
  static constexpr u16 enc(int s, int f, int k) {
    return (u16)(s | (f << 5) | (k << 9));
  }
  constexpr void p3(int base, int F, int src) {
    v[base + 0] = enc(src + 0, 0, 0);
    v[base + 1] = enc(src + 1, 0, 0);
    v[base + 2] = enc(src + 2, 0, 0);
    for (int f = 0; f < F; ++f)
      for (int r = 0; r < 6; ++r) {
        int comp = (r < 3) ? r : r - 3;
        v[base + 3 + f * 6 + r] = enc(src + comp, f, (r < 3) ? 1 : 2);
      }
  }
  constexpr void p1(int base, int F, int src) {
    v[base] = enc(src, 0, 0);
    for (int f = 0; f < F; ++f) {
      v[base + 1 + 2 * f] = enc(src, f, 1);
      v[base + 2 + 2 * f] = enc(src, f, 2);
    }
  }
  constexpr FT() : v{} {
    p3(0, 10, 0);     // hit_pos_emb   (q)          [0..62]
    p1(63, 4, 3);     // density_emb                [63..71]
    p3(72, 10, 4);    // smoothed_emb  (sp)         [72..134]
    p3(135, 10, 7);   // var_emb       (var)        [135..197]
    p3(198, 4, 10);   // hit_dir_emb   (ray dir)    [198..224]
    p3(225, 4, 13);   // dirs_emb      (dir)        [225..251]
    v[252] = enc(16, 0, 0);  // normals
    v[253] = enc(17, 0, 0);
    v[254] = enc(18, 0, 0);
    v[255] = enc(0, 0, 3);   // pad col
  }
};
__constant__ FT ftab = FT();

// ---------------------------------------------------------------------------
// Kernel 1: weight prep fp32 -> fp16, BK=32 swizzled layout.
// W0 [256,511] -> [256,512]: col 255 = 0, cols 256..511 = orig 255..510.
// ---------------------------------------------------------------------------
__global__ __launch_bounds__(256) void prep_weights(
    const float* __restrict__ W0, const float* __restrict__ W1,
    const float* __restrict__ W2,
    f16* __restrict__ w0f, f16* __restrict__ w1f, f16* __restrict__ w2f)
{
  int i = blockIdx.x * 256 + threadIdx.x;   // 0 .. 262143
  float v; f16* pf; int n, c;
  if (i < 131072) {
    n = i >> 9; c = i & 511;
    v = (c < 255) ? W0[n * 511 + c] : ((c == 255) ? 0.0f : W0[n * 511 + (c - 1)]);
    pf = w0f;
  } else if (i < 196608) {
    int j = i - 131072; n = j >> 8; c = j & 255; v = W1[j]; pf = w1f;
  } else {
    int j = i - 196608; n = j >> 8; c = j & 255; v = W2[j]; pf = w2f;
  }
  int kt = c >> 5, g = (c >> 3) & 3, jj = c & 7;
  int u = n * 4 + (g ^ ((n >> 1) & 3));
  pf[kt * 8192 + u * 8 + jj] = (f16)v;
}

// ---------------------------------------------------------------------------
// Kernel 2: ball query + features -> swizzled fp16 X [24576,256].
// 1 wave/query, 16 queries/block; inline accumulate (r6 structure, proven).
// ---------------------------------------------------------------------------
__global__ __launch_bounds__(1024) void feat_kernel(
    const float* __restrict__ points, const float* __restrict__ normals,
    const float* __restrict__ parts, const float* __restrict__ rays,
    const float* __restrict__ ro, f16* __restrict__ Xf)
{
  __shared__ float2 pxy[4096];
  __shared__ float  pzs[4096];
  __shared__ float  sdata[16][20];

  const int tid = threadIdx.x;
  for (int j = tid; j < 4096; j += 1024) {
    pxy[j] = make_float2(parts[3 * j + 0], parts[3 * j + 1]);
    pzs[j] = parts[3 * j + 2];
  }
  __syncthreads();

  const int lane = tid & 63, wv = tid >> 6;
  const int q = blockIdx.x * 16 + wv;
  const float qx = points[3 * q], qy = points[3 * q + 1], qz = points[3 * q + 2];
  const float RQ = 0.1f * 0.1f;

  int nAcc = 0, total = 0;
  float sdx = 0, sdy = 0, sdz = 0;
  float s2x = 0, s2y = 0, s2z = 0;
  float sw = 0, swx = 0, swy = 0, swz = 0;

  for (int jr = 0; jr < 64; ++jr) {
    float2 xy = pxy[jr * 64 + lane];
    float z = pzs[jr * 64 + lane];
    float ex = xy.x - qx, ey = xy.y - qy, ez = z - qz;
    float d2 = __fadd_rn(__fadd_rn(__fmul_rn(ex, ex), __fmul_rn(ey, ey)), __fmul_rn(ez, ez));
    bool hit = d2 < RQ;
    unsigned long long m = __ballot(hit);
    int pos = __builtin_amdgcn_mbcnt_hi((unsigned)(m >> 32),
              __builtin_amdgcn_mbcnt_lo((unsigned)m, 0u));
    if (hit && (total + pos < 16)) {
      nAcc++;
      sdx += ex; sdy += ey; sdz += ez;
      s2x += ex * ex; s2y += ey * ey; s2z += ez * ez;
      float dn = sqrtf(d2);
      float t = dn * 10.0f;
      float w = fmaxf(1.0f - t * t * t, 0.0f);
      sw += w; swx += w * xy.x; swy += w * xy.y; swz += w * z;
    }
    total += __popcll(m);
    if (total >= 16) break;
  }

  #define WRED(x) { _Pragma("unroll") for (int o = 32; o; o >>= 1) x += __shfl_xor(x, o, 64); }
  float fn = (float)nAcc;
  WRED(fn); WRED(sdx); WRED(sdy); WRED(sdz);
  WRED(s2x); WRED(s2y); WRED(s2z);
  WRED(sw); WRED(swx); WRED(swy); WRED(swz);
  #undef WRED

  float tq = sqrtf(qx * qx + qy * qy + qz * qz) * 10.0f;
  float wpad = fmaxf(1.0f - tq * tq * tq, 0.0f);
  float density = sw + (16.0f - fn) * wpad;
  float invd = 1.0f / (density + 1e-12f);
  float spx = swx * invd, spy = swy * invd, spz = swz * invd;

  float invn = 1.0f / (fn + 1e-12f);
  float mx = sdx * invn, my = sdy * invn, mz = sdz * invn;
  float vx = fmaxf((s2x - 2.0f * mx * sdx + fn * mx * mx) * invn, 0.0f);
  float vy = fmaxf((s2y - 2.0f * my * sdy + fn * my * my) * invn, 0.0f);
  float vz = fmaxf((s2z - 2.0f * mz * sdz + fn * mz * mz) * invn, 0.0f);

  float dxx = spx - ro[0], dyy = spy - ro[1], dzz = spz - ro[2];
  float il = 1.0f / sqrtf(dxx * dxx + dyy * dyy + dzz * dzz);

  if (lane == 0) {
    float* s = sdata[wv];
    s[0] = qx; s[1] = qy; s[2] = qz; s[3] = density;
    s[4] = spx; s[5] = spy; s[6] = spz;
    s[7] = vx; s[8] = vy; s[9] = vz;
    int r = q / 48;
    s[10] = rays[6 * r + 3]; s[11] = rays[6 * r + 4]; s[12] = rays[6 * r + 5];
    s[13] = dxx * il; s[14] = dyy * il; s[15] = dzz * il;
    s[16] = normals[3 * q]; s[17] = normals[3 * q + 1]; s[18] = normals[3 * q + 2];
  }
  __syncthreads();

  const int b = q / 48, m48 = q % 48;
  const size_t base = (size_t)b * 12288;
  #pragma unroll
  for (int it = 0; it < 4; ++it) {
    int c = it * 64 + lane;
    int e = ftab.v[c];
    float sv = sdata[wv][e & 31];
    float arg = sv * (float)(1 << ((e >> 5) & 15));
    float sn, cs;
    sincosf(arg, &sn, &cs);
    int kind = e >> 9;
    float val = (kind == 0) ? sv : (kind == 1 ? sn : (kind == 2 ? cs : 0.0f));
    int kt = c >> 5, g = (c >> 3) & 3, j = c & 7;
    int u = m48 * 4 + (g ^ ((m48 >> 1) & 3));
    Xf[base + kt * 1536 + u * 8 + j] = (f16)val;
  }
}

// ---------------------------------------------------------------------------
// Kernel 3: fused 3-layer fp16 MFMA MLP + final 256->3 + sigmoid.
// 512 blocks x 256 thr (4 waves, wave tile 48x64), 48 rows/block, 40 KB LDS
// -> 2 blocks/CU. K-loop: drain -> frags to regs -> barrier -> stage(kt+1)
// -> MFMA(kt). One f16 MFMA per fragment pair, fp32 accumulate.
// LDS: Hf [0,24576) | Bs [24576,40960); A-stage aliases Hf[0,3072); w3s
// aliases Bs in the final phase.
// ---------------------------------------------------------------------------
__global__ __launch_bounds__(256, 2) void fused_mlp(
    const f16* __restrict__ Xf, const float* __restrict__ fvec,
    const f16* __restrict__ w0f, const f16* __restrict__ w1f,
    const f16* __restrict__ w2f,
    const float* __restrict__ b0, const float* __restrict__ b1,
    const float* __restrict__ b2,
    const float* __restrict__ W3, const float* __restrict__ b3,
    float* __restrict__ out)
{
  extern __shared__ char lds[];
  f16* Hf    = (f16*)lds;                 // 24576 B
  f16* Bs    = (f16*)(lds + 24576);       // 16384 B
  f16* Ah_st = (f16*)lds;                 // 3072 B (L0 only)
  float* w3s = (float*)(lds + 24576);

  const int tid = threadIdx.x, lane = tid & 63, wn = tid >> 6;
  const int l15 = lane & 15, l4 = lane >> 4;
  const int blk = blockIdx.x;

  if (blk & 1) __builtin_amdgcn_s_sleep(8);   // de-phase co-resident blocks

  f32x4 acc[3][4];

  const f16* Xft = Xf + (size_t)blk * 12288;

  auto stageB = [&](const f16* wf, int kt) {
    #pragma unroll
    for (int s = 0; s < 4; ++s) {
      int ch = wn + s * 4;                // 0..15, 1 KB chunks
      glds16(wf + kt * 8192 + ch * 512 + lane * 8, Bs + ch * 512 + lane * 8);
    }
  };
  auto stageA = [&](int kt) {
    if (kt < 8) {
      if (wn < 3)
        glds16(Xft + kt * 1536 + wn * 512 + lane * 8, Ah_st + wn * 512 + lane * 8);
    } else {
      if (tid < 192) {
        int m = tid >> 2, g = tid & 3;
        const float* src = fvec + (size_t)(blk * 48 + m) * 256 + (kt - 8) * 32 + g * 8;
        float4 v0 = ((const float4*)src)[0];
        float4 v1 = ((const float4*)src)[1];
        f16 hs[8] = {(f16)v0.x, (f16)v0.y, (f16)v0.z, (f16)v0.w,
                     (f16)v1.x, (f16)v1.y, (f16)v1.z, (f16)v1.w};
        int u = m * 4 + (g ^ ((m >> 1) & 3));
        *(uint4*)(Ah_st + u * 8) = *(uint4*)hs;
      }
    }
  };
  auto bfrags = [&](f16x8* bf) {
    #pragma unroll
    for (int j = 0; j < 4; ++j) {
      int n = wn * 64 + j * 16 + l15;
      int u = n * 4 + (l4 ^ ((n >> 1) & 3));
      bf[j] = __builtin_bit_cast(f16x8, *(const uint4*)(Bs + u * 8));
    }
  };
  auto mfmas = [&](f16x8* af, f16x8* bf) {
    #pragma unroll
    for (int i = 0; i < 3; ++i)
      #pragma unroll
      for (int j = 0; j < 4; ++j)
        acc[i][j] = __builtin_amdgcn_mfma_f32_16x16x32_f16(af[i], bf[j], acc[i][j], 0, 0, 0);
  };
  auto epilogue = [&](const float* bias_) {
    float bv[4];
    #pragma unroll
    for (int j = 0; j < 4; ++j) bv[j] = bias_[wn * 64 + j * 16 + l15];
    #pragma unroll
    for (int i = 0; i < 3; ++i) {
      #pragma unroll
      for (int r = 0; r < 4; ++r) {
        int m = i * 16 + l4 * 4 + r;
        #pragma unroll
        for (int j = 0; j < 4; ++j) {
          int n = wn * 64 + j * 16 + l15;
          float v = fmaxf(acc[i][j][r] + bv[j], 0.0f);
          int u = m * 32 + ((n >> 3) ^ ((m >> 1) & 7));
          Hf[u * 8 + (n & 7)] = (f16)v;
        }
      }
    }
  };

  // ======================= L0: K=512 (8 kt from X, 8 from fvec) ============
  #pragma unroll
  for (int i = 0; i < 3; ++i)
    #pragma unroll
    for (int j = 0; j < 4; ++j) acc[i][j] = (f32x4){0, 0, 0, 0};

  stageA(0);
  stageB(w0f, 0);
  for (int kt = 0; kt < 16; ++kt) {
    __syncthreads();                       // drain stage(kt)
    f16x8 af[3], bf[4];
    #pragma unroll
    for (int i = 0; i < 3; ++i) {
      int m = i * 16 + l15;
      int u = m * 4 + (l4 ^ ((m >> 1) & 3));
      af[i] = __builtin_bit_cast(f16x8, *(const uint4*)(Ah_st + u * 8));
    }
    bfrags(bf);
    __syncthreads();                       // all reads in regs
    if (kt < 15) { stageA(kt + 1); stageB(w0f, kt + 1); }
    mfmas(af, bf);
  }
  epilogue(b0);

  // ======================= L1, L2: K=256, A from Hf ========================
  #pragma unroll 1
  for (int layer = 0; layer < 2; ++layer) {
    const f16* wf = layer ? w2f : w1f;
    #pragma unroll
    for (int i = 0; i < 3; ++i)
      #pragma unroll
      for (int j = 0; j < 4; ++j) acc[i][j] = (f32x4){0, 0, 0, 0};

    stageB(wf, 0);
    for (int kt = 0; kt < 8; ++kt) {
      __syncthreads();                     // kt=0 also fences epilogue H writes
      f16x8 af[3], bf[4];
      #pragma unroll
      for (int i = 0; i < 3; ++i) {
        int m = i * 16 + l15;
        int g = kt * 4 + l4;
        int u = m * 32 + (g ^ ((m >> 1) & 7));
        af[i] = __builtin_bit_cast(f16x8, *(const uint4*)(Hf + u * 8));
      }
      bfrags(bf);
      __syncthreads();
      if (kt < 7) stageB(wf, kt + 1);
      mfmas(af, bf);
    }
    epilogue(layer ? b2 : b1);
  }

  // ======================= final: 256 -> 3 + sigmoid =======================
  __syncthreads();                         // H complete, B region free
  for (int i = tid; i < 768; i += 256) w3s[i] = W3[i];
  __syncthreads();

  const float B30 = b3[0], B31 = b3[1], B32 = b3[2];
  #pragma unroll 1
  for (int rr = 0; rr < 12; ++rr) {
    int m = wn * 12 + rr;
    int g = lane >> 1, j0 = (lane & 1) * 4;
    int u = m * 32 + (g ^ ((m >> 1) & 7));
    uint2 pk = *(const uint2*)(Hf + u * 8 + j0);
    f16 h4[4];
    *(uint2*)h4 = pk;
    float h0 = (float)h4[0], h1 = (float)h4[1], h2 = (float)h4[2], h3 = (float)h4[3];
    int kc = lane * 4;
    float4 wa = *(const float4*)(w3s + kc);
    float4 wb = *(const float4*)(w3s + 256 + kc);
    float4 wc = *(const float4*)(w3s + 512 + kc);
    float p0 = fmaf(h3, wa.w, fmaf(h2, wa.z, fmaf(h1, wa.y, h0 * wa.x)));
    float p1 = fmaf(h3, wb.w, fmaf(h2, wb.z, fmaf(h1, wb.y, h0 * wb.x)));
    float p2 = fmaf(h3, wc.w, fmaf(h2, wc.z, fmaf(h1, wc.y, h0 * wc.x)));
    #pragma unroll
    for (int o = 32; o; o >>= 1) {
      p0 += __shfl_xor(p0, o, 64);
      p1 += __shfl_xor(p1, o, 64);
      p2 += __shfl_xor(p2, o, 64);
    }
    if (lane == 0) {
      size_t ro_ = (size_t)(blk * 48 + m) * 3;
      out[ro_ + 0] = 1.0f / (1.0f + expf(-(p0 + B30)));
      out[ro_ + 1] = 1.0f / (1.0f + expf(-(p1 + B31)));
      out[ro_ + 2] = 1.0f / (1.0f + expf(-(p2 + B32)));
    }
  }
}

// ---------------------------------------------------------------------------
extern "C" void kernel_launch(void* const* d_in, const int* in_sizes, int n_in,
                              void* d_out, int out_size, void* d_ws, size_t ws_size,
                              hipStream_t stream) {
  const float* points  = (const float*)d_in[0];
  const float* normals = (const float*)d_in[1];
  const float* fvec    = (const float*)d_in[3];
  const float* parts   = (const float*)d_in[5];
  const float* rays    = (const float*)d_in[6];
  const float* ro      = (const float*)d_in[7];
  const float* W0 = (const float*)d_in[8];
  const float* b0 = (const float*)d_in[9];
  const float* W1 = (const float*)d_in[10];
  const float* b1 = (const float*)d_in[11];
  const float* W2 = (const float*)d_in[12];
  const float* b2 = (const float*)d_in[13];
  const float* W3 = (const float*)d_in[14];
  const float* b3 = (const float*)d_in[15];

  char* ws = (char*)d_ws;
  f16* Xf  = (f16*)(ws);                    // [24576,256] fp16 swizzled, 12.58 MB
  f16* w0f = (f16*)(ws + 12582912);         // 262144 B
  f16* w1f = (f16*)(ws + 12845056);         // 131072 B
  f16* w2f = (f16*)(ws + 12976128);         // 131072 B
  float* out = (float*)d_out;

  (void)hipFuncSetAttribute((const void*)fused_mlp,
                            hipFuncAttributeMaxDynamicSharedMemorySize, 40960);

  prep_weights<<<1024, 256, 0, stream>>>(W0, W1, W2, w0f, w1f, w2f);
  feat_kernel<<<1536, 1024, 0, stream>>>(points, normals, parts, rays, ro, Xf);
  fused_mlp<<<512, 256, 40960, stream>>>(Xf, fvec, w0f, w1f, w2f,
                                         b0, b1, b2, W3, b3, out);
}